// Round 19
// baseline (405.773 us; speedup 1.0000x reference)
//
#include <hip/hip_runtime.h>
#include <hip/hip_bf16.h>
#include <stdint.h>

typedef short s16x8 __attribute__((ext_vector_type(8)));
typedef short s16x4 __attribute__((ext_vector_type(4)));
typedef float f32x4 __attribute__((ext_vector_type(4)));

#define MFMA16(a, b, c) __builtin_amdgcn_mfma_f32_16x16x32_bf16((a), (b), (c), 0, 0, 0)

__device__ __forceinline__ unsigned short f2bf(float f) {
  union { float f; uint32_t u; } x; x.f = f;
  uint32_t u = x.u;
  return (unsigned short)((u + 0x7FFFu + ((u >> 16) & 1u)) >> 16);
}
__device__ __forceinline__ float bf2f(unsigned short h) {
  union { uint32_t u; float f; } x; x.u = ((uint32_t)h) << 16;
  return x.f;
}
__device__ __forceinline__ void glds16(const void* g, void* l) {
  __builtin_amdgcn_global_load_lds((const __attribute__((address_space(1))) void*)g,
                                   (__attribute__((address_space(3))) void*)l, 16, 0, 0);
}

// ---------------- prep kernels ----------------
// ws: wt[4][192][192] bf16 (Wt[n][k]=W[k][n]) | rpb[6][64][64] bf16 | QKV scratch
__global__ __launch_bounds__(256) void prep_weights(
    const float* __restrict__ Wq, const float* __restrict__ Wk,
    const float* __restrict__ Wv, const float* __restrict__ Wp,
    unsigned short* __restrict__ wt) {
  int idx = blockIdx.x * 256 + threadIdx.x;
  if (idx >= 4 * 36864) return;
  int mat = idx / 36864, rem = idx % 36864;
  int n = rem / 192, k = rem % 192;
  const float* W = (mat == 0) ? Wq : (mat == 1) ? Wk : (mat == 2) ? Wv : Wp;
  wt[idx] = f2bf(W[k * 192 + n]);
}

__global__ __launch_bounds__(256) void prep_rpb(
    const float* __restrict__ bias_table, unsigned short* __restrict__ rpb) {
  int idx = blockIdx.x * 256 + threadIdx.x;
  if (idx >= 6 * 4096) return;
  int h = idx / 4096, r = idx % 4096;
  int i = r >> 6, j = r & 63;
  int dh = (i >> 3) - (j >> 3) + 7;
  int dw = (i & 7) - (j & 7) + 7;
  rpb[idx] = f2bf(bias_table[(dh * 15 + dw) * 6 + h]);
}

// ---------------- pass 1 (r12 + nontemporal X loads) -------------------------
// Per-window scratch (73728 B):
//   [Q 64x192 bf16 chunk-swizzled | K same | VT 192x64 bf16 k-permuted+swizzled]
__global__ __launch_bounds__(256, 3) void pass1_proj(
    const float* __restrict__ X1g, const float* __restrict__ X2g,
    const float* __restrict__ X3g,
    const float* __restrict__ bq, const float* __restrict__ bk,
    const float* __restrict__ bv,
    const unsigned short* __restrict__ wt,
    char* __restrict__ qkv, int B_) {
  extern __shared__ char p1lds[];   // [0,25600): X bf16 [64][200]; [25600,50176): out
  unsigned short* xs = (unsigned short*)p1lds;
  char* ob = p1lds + 25600;
  const int which = blockIdx.x / B_;
  const int w = blockIdx.x - which * B_;
  const int tid = threadIdx.x;
  const int lane = tid & 63;
  const int wv = tid >> 6;
  const int l16 = lane & 15, lq = lane >> 4;
  const float* Xb =
      ((which == 0) ? X1g : (which == 1) ? X2g : X3g) + (size_t)w * 12288;
  const unsigned short* W = wt + which * 36864;
  const int nt0 = wv * 3;

  // reg-stage X: 6 float8-pairs per thread (coalesced, read-once -> nontemporal)
  const f32x4* Xb4 = (const f32x4*)Xb;
  f32x4 xr[12];
#pragma unroll
  for (int r = 0; r < 6; ++r) {
    int p = r * 256 + tid;           // pair index 0..1535
    xr[2 * r]     = __builtin_nontemporal_load(&Xb4[2 * p]);
    xr[2 * r + 1] = __builtin_nontemporal_load(&Xb4[2 * p + 1]);
  }

  // weight fragments + bias (L2; latency hides under X loads)
  s16x8 wf[3][6];
#pragma unroll
  for (int t = 0; t < 3; ++t) {
    const unsigned short* wc = W + (size_t)((nt0 + t) * 16 + l16) * 192 + lq * 8;
#pragma unroll
    for (int ks = 0; ks < 6; ++ks) wf[t][ks] = *(const s16x8*)(wc + ks * 32);
  }
  f32x4 bqk[3];
  float bvv[3];
  if (which < 2) {
    const float* bias = which ? bk : bq;
#pragma unroll
    for (int t = 0; t < 3; ++t)
      bqk[t] = *(const f32x4*)&bias[(nt0 + t) * 16 + lq * 4];
  } else {
#pragma unroll
    for (int t = 0; t < 3; ++t) bvv[t] = bv[(nt0 + t) * 16 + l16];
  }

  // convert + write bf16 X tile [64][200]
#pragma unroll
  for (int r = 0; r < 6; ++r) {
    int p = r * 256 + tid;
    int row = p / 24, k8 = p - row * 24;
    const f32x4& a = xr[2 * r];
    const f32x4& c = xr[2 * r + 1];
    s16x8 t;
    t[0] = (short)f2bf(a[0]); t[1] = (short)f2bf(a[1]);
    t[2] = (short)f2bf(a[2]); t[3] = (short)f2bf(a[3]);
    t[4] = (short)f2bf(c[0]); t[5] = (short)f2bf(c[1]);
    t[6] = (short)f2bf(c[2]); t[7] = (short)f2bf(c[3]);
    *(s16x8*)&xs[row * 200 + k8 * 8] = t;
  }
  __syncthreads();

  const float scale = (which == 0) ? 0.17677669529663689f : 1.0f;  // 32^-0.5

#pragma unroll
  for (int mi = 0; mi < 4; ++mi) {
    s16x8 xf[6];
    const unsigned short* pr = xs + (mi * 16 + l16) * 200 + lq * 8;
#pragma unroll
    for (int ks = 0; ks < 6; ++ks) xf[ks] = *(const s16x8*)(pr + ks * 32);
    if (which < 2) {
      // swapped mfma: D[dim rows, tok cols]; lane: tok = mi*16+l16, dims lq*4..+3
      int tok = mi * 16 + l16;
#pragma unroll
      for (int t = 0; t < 3; ++t) {
        f32x4 acc = bqk[t];
#pragma unroll
        for (int ks = 0; ks < 6; ++ks) acc = MFMA16(wf[t][ks], xf[ks], acc);
        s16x4 pv;
#pragma unroll
        for (int q = 0; q < 4; ++q) pv[q] = (short)f2bf(acc[q] * scale);
        int c = (nt0 + t) * 2 + (lq >> 1);                    // 16B chunk (dims c*8..)
        *(s16x4*)(ob + tok * 384 + ((c ^ (tok & 7)) << 4) + (lq & 1) * 8) = pv;
      }
    } else {
      // unswapped: D[tok rows, dim cols]; VT[d][slot], slot k-permuted+swizzled
#pragma unroll
      for (int t = 0; t < 3; ++t) {
        f32x4 acc = {bvv[t], bvv[t], bvv[t], bvv[t]};
#pragma unroll
        for (int ks = 0; ks < 6; ++ks) acc = MFMA16(xf[ks], wf[t][ks], acc);
        int d = (nt0 + t) * 16 + l16;
        int c = (mi >> 1) * 4 + lq;
        s16x4 pv;
#pragma unroll
        for (int q = 0; q < 4; ++q) pv[q] = (short)f2bf(acc[q]);
        *(s16x4*)(ob + d * 128 + ((c ^ (d & 7)) << 4) + (mi & 1) * 8) = pv;
      }
    }
  }
  __syncthreads();

  // copy out-image -> global, full-line coalesced (1536 chunks of 16B)
  char* gdst = qkv + (size_t)w * 73728 + which * 24576;
#pragma unroll
  for (int r = 0; r < 6; ++r) {
    int i = (r * 256 + tid) * 16;
    *(float4*)(gdst + i) = *(const float4*)(ob + i);
  }
}

// ---------------- pass 2 (r12 + nontemporal out stores) ----------------------
// LDS: [K 24576 swz | VT 24576 swz | O 64x208 u16 = 26624] = 75776 B
__global__ __launch_bounds__(512, 4) void pass2_attn(
    const char* __restrict__ qkv, const float* __restrict__ maskg,
    const unsigned short* __restrict__ rpb, const float* __restrict__ bp,
    const unsigned short* __restrict__ wt, float* __restrict__ out, int nW) {
  extern __shared__ char lds[];
  const int b = blockIdx.x, tid = threadIdx.x;
  const int wv = tid >> 6, lane = tid & 63;
  const int l16 = lane & 15, lq = lane >> 4;
  const char* Qg = qkv + (size_t)b * 73728;       // swizzled layout (see pass1)
  const char* KVsrc = Qg + 24576;

  // stage K + VT (pre-swizzled by pass1, linear copy): 3072 chunks, 6 rounds
#pragma unroll
  for (int r = 0; r < 6; ++r)
    glds16(KVsrc + (size_t)(r * 512 + tid) * 16, lds + (r * 512 + wv * 64) * 16);

  // register prefetch (completes under the staging drain)
  const int mt = wv & 3, g = wv >> 2;
  const int row0 = mt * 16, qg = row0 + l16;
  s16x8 qf[3];
#pragma unroll
  for (int hh = 0; hh < 3; ++hh) {
    int c = (g * 3 + hh) * 4 + lq;                 // chunk = dim/8
    qf[hh] = *(const s16x8*)(Qg + qg * 384 + ((c ^ (qg & 7)) << 4));
  }
  const float* mrow = maskg + (size_t)(b % nW) * 4096 + qg * 64;
  f32x4 mv[4];
#pragma unroll
  for (int nt = 0; nt < 4; ++nt) mv[nt] = *(const f32x4*)(mrow + nt * 16 + lq * 4);
  s16x4 rv[3][4];
#pragma unroll
  for (int hh = 0; hh < 3; ++hh)
#pragma unroll
    for (int nt = 0; nt < 4; ++nt)
      rv[hh][nt] = *(const s16x4*)&rpb[(g * 3 + hh) * 4096 + qg * 64 + nt * 16 + lq * 4];
  __syncthreads();

  unsigned short* Osm = (unsigned short*)(lds + 49152);   // [64][208]
#pragma unroll
  for (int hh = 0; hh < 3; ++hh) {
    int h = g * 3 + hh;
    f32x4 sv[4];
#pragma unroll
    for (int nt = 0; nt < 4; ++nt) {
      int kr = nt * 16 + l16;
      s16x8 ka = *(const s16x8*)(lds + kr * 384 + (((h * 4 + lq) ^ (kr & 7)) << 4));
      f32x4 z = {0.f, 0.f, 0.f, 0.f};
      sv[nt] = MFMA16(ka, qf[hh], z);   // lane l16 = q-tok, regs = k-toks
    }
    float lg[4][4];
#pragma unroll
    for (int nt = 0; nt < 4; ++nt)
#pragma unroll
      for (int qr = 0; qr < 4; ++qr)
        lg[nt][qr] = sv[nt][qr] + bf2f((unsigned short)rv[hh][nt][qr]) + mv[nt][qr];
    float mx = lg[0][0];
#pragma unroll
    for (int nt = 0; nt < 4; ++nt)
#pragma unroll
      for (int qr = 0; qr < 4; ++qr) mx = fmaxf(mx, lg[nt][qr]);
    mx = fmaxf(mx, __shfl_xor(mx, 16, 64));
    mx = fmaxf(mx, __shfl_xor(mx, 32, 64));
    float p[4][4], sum = 0.f;
#pragma unroll
    for (int nt = 0; nt < 4; ++nt)
#pragma unroll
      for (int qr = 0; qr < 4; ++qr) {
        p[nt][qr] = __expf(lg[nt][qr] - mx);
        sum += p[nt][qr];
      }
    sum += __shfl_xor(sum, 16, 64);
    sum += __shfl_xor(sum, 32, 64);
    float ri = 1.0f / sum;
    s16x8 pa0, pa1;
#pragma unroll
    for (int r = 0; r < 4; ++r) {
      pa0[r]     = (short)f2bf(p[0][r] * ri);
      pa0[4 + r] = (short)f2bf(p[1][r] * ri);
      pa1[r]     = (short)f2bf(p[2][r] * ri);
      pa1[4 + r] = (short)f2bf(p[3][r] * ri);
    }
    // PV: P (regs) x VT (LDS, k-permuted + swizzled)
    f32x4 o0 = {0.f, 0.f, 0.f, 0.f};
    f32x4 o1 = {0.f, 0.f, 0.f, 0.f};
#pragma unroll
    for (int kt = 0; kt < 2; ++kt) {
      int d0 = h * 32 + l16, d1 = h * 32 + 16 + l16;
      s16x8 vb0 = *(const s16x8*)(lds + 24576 + d0 * 128 +
                                  ((((kt << 2) + lq) ^ (d0 & 7)) << 4));
      s16x8 vb1 = *(const s16x8*)(lds + 24576 + d1 * 128 +
                                  ((((kt << 2) + lq) ^ (d1 & 7)) << 4));
      o0 = MFMA16(kt ? pa1 : pa0, vb0, o0);
      o1 = MFMA16(kt ? pa1 : pa0, vb1, o1);
    }
#pragma unroll
    for (int q = 0; q < 4; ++q) {
      int row = row0 + lq * 4 + q;
      Osm[row * 208 + h * 32 + l16]      = f2bf(o0[q]);
      Osm[row * 208 + h * 32 + 16 + l16] = f2bf(o1[q]);
    }
  }
  __syncthreads();

  // out = O @ Wp + bp  (never re-read -> nontemporal stores)
  {
    const unsigned short* W = wt + 3 * 36864;
    float* obp = out + (size_t)b * 12288;
    const int mh = wv >> 2, nh = wv & 3;
    s16x8 a[2][6];
#pragma unroll
    for (int mi = 0; mi < 2; ++mi)
#pragma unroll
      for (int ks = 0; ks < 6; ++ks)
        a[mi][ks] = *(const s16x8*)&Osm[((mh * 2 + mi) * 16 + l16) * 208 +
                                        ks * 32 + lq * 8];
#pragma unroll
    for (int nt2 = 0; nt2 < 3; ++nt2) {
      int col = (nh * 3 + nt2) * 16 + l16;
      float bsv = bp[col];
      f32x4 acc0 = {bsv, bsv, bsv, bsv};
      f32x4 acc1 = {bsv, bsv, bsv, bsv};
      const unsigned short* wc = W + (size_t)col * 192 + lq * 8;
#pragma unroll
      for (int ks = 0; ks < 6; ++ks) {
        s16x8 bb = *(const s16x8*)(wc + ks * 32);
        acc0 = MFMA16(a[0][ks], bb, acc0);
        acc1 = MFMA16(a[1][ks], bb, acc1);
      }
#pragma unroll
      for (int q = 0; q < 4; ++q) {
        __builtin_nontemporal_store(
            acc0[q], &obp[((mh * 2 + 0) * 16 + lq * 4 + q) * 192 + col]);
        __builtin_nontemporal_store(
            acc1[q], &obp[((mh * 2 + 1) * 16 + lq * 4 + q) * 192 + col]);
      }
    }
  }
}

// ---------------- fallback: r1 fused single kernel (proven) ----------------
#define XPAD 200
#define VPAD 72
#define PPAD 72
#define MPAD 66
struct SmemF {
  unsigned short Xs[2][64][XPAD];
  unsigned short Qs[64][XPAD];
  unsigned short Ks[64][XPAD];
  unsigned short VTs[192][VPAD];
  unsigned short Ps[2][64][PPAD];
  unsigned short Ms[64][MPAD];
};

__global__ __launch_bounds__(512, 2) void win_attn_fused(
    const float* __restrict__ X1g, const float* __restrict__ X2g,
    const float* __restrict__ X3g, const float* __restrict__ maskg,
    const float* __restrict__ bq, const float* __restrict__ bk,
    const float* __restrict__ bv, const float* __restrict__ bp,
    const unsigned short* __restrict__ wt, const unsigned short* __restrict__ rpb,
    float* __restrict__ out, int nW) {
  extern __shared__ char smem_raw[];
  SmemF& S = *reinterpret_cast<SmemF*>(smem_raw);
  const int b = blockIdx.x;
  const int tid = threadIdx.x;
  const int wave = tid >> 6, lane = tid & 63;
  const int l16 = lane & 15, lq = lane >> 4;
  const int mh = wave >> 2, nh = wave & 3;

  const float4* x1v = (const float4*)(X1g + (size_t)b * 12288);
  const float4* x2v = (const float4*)(X2g + (size_t)b * 12288);
  const float4* x3v = (const float4*)(X3g + (size_t)b * 12288);
  float4 x3r[6];
#pragma unroll
  for (int it = 0; it < 6; ++it) {
    int i = it * 512 + tid;
    float4 v1 = x1v[i];
    float4 v2 = x2v[i];
    x3r[it] = x3v[i];
    int row = i / 48, c = (i % 48) * 4;
    s16x4 p1, p2;
    p1[0] = (short)f2bf(v1.x); p1[1] = (short)f2bf(v1.y);
    p1[2] = (short)f2bf(v1.z); p1[3] = (short)f2bf(v1.w);
    p2[0] = (short)f2bf(v2.x); p2[1] = (short)f2bf(v2.y);
    p2[2] = (short)f2bf(v2.z); p2[3] = (short)f2bf(v2.w);
    *(s16x4*)&S.Xs[0][row][c] = p1;
    *(s16x4*)&S.Xs[1][row][c] = p2;
  }
  const float* mw = maskg + (size_t)(b % nW) * 4096;
  for (int i = tid; i < 4096; i += 512)
    S.Ms[i >> 6][i & 63] = f2bf(mw[i]);
  __syncthreads();

  auto proj = [&](const unsigned short (*Xsrc)[XPAD], const unsigned short* W,
                  const float* bias, unsigned short (*dst)[XPAD], float scale) {
    s16x8 a[2][6];
#pragma unroll
    for (int mi = 0; mi < 2; ++mi)
#pragma unroll
      for (int ks = 0; ks < 6; ++ks)
        a[mi][ks] = *(const s16x8*)&Xsrc[(mh * 2 + mi) * 16 + l16][ks * 32 + lq * 8];
#pragma unroll
    for (int nt2 = 0; nt2 < 3; ++nt2) {
      int col = (nh * 3 + nt2) * 16 + l16;
      float bsv = bias[col];
      f32x4 acc0 = {bsv, bsv, bsv, bsv};
      f32x4 acc1 = {bsv, bsv, bsv, bsv};
#pragma unroll
      for (int ks = 0; ks < 6; ++ks) {
        s16x8 bb = *(const s16x8*)&W[(size_t)col * 192 + ks * 32 + lq * 8];
        acc0 = MFMA16(a[0][ks], bb, acc0);
        acc1 = MFMA16(a[1][ks], bb, acc1);
      }
#pragma unroll
      for (int q = 0; q < 4; ++q) {
        dst[(mh * 2 + 0) * 16 + lq * 4 + q][col] = f2bf(acc0[q] * scale);
        dst[(mh * 2 + 1) * 16 + lq * 4 + q][col] = f2bf(acc1[q] * scale);
      }
    }
  };

  proj(S.Xs[0], wt + 0 * 36864, bq, S.Qs, 0.17677669529663689f);
  proj(S.Xs[1], wt + 1 * 36864, bk, S.Ks, 1.0f);
  __syncthreads();

#pragma unroll
  for (int it = 0; it < 6; ++it) {
    int i = it * 512 + tid;
    int row = i / 48, c = (i % 48) * 4;
    s16x4 p3;
    p3[0] = (short)f2bf(x3r[it].x); p3[1] = (short)f2bf(x3r[it].y);
    p3[2] = (short)f2bf(x3r[it].z); p3[3] = (short)f2bf(x3r[it].w);
    *(s16x4*)&S.Xs[0][row][c] = p3;
  }
  __syncthreads();

  {
    const unsigned short* W = wt + 2 * 36864;
    s16x8 a[2][6];
#pragma unroll
    for (int mi = 0; mi < 2; ++mi)
#pragma unroll
      for (int ks = 0; ks < 6; ++ks)
        a[mi][ks] = *(const s16x8*)&S.Xs[0][(mh * 2 + mi) * 16 + l16][ks * 32 + lq * 8];
#pragma unroll
    for (int nt2 = 0; nt2 < 3; ++nt2) {
      int col = (nh * 3 + nt2) * 16 + l16;
      float bsv = bv[col];
      f32x4 acc0 = {bsv, bsv, bsv, bsv};
      f32x4 acc1 = {bsv, bsv, bsv, bsv};
#pragma unroll
      for (int ks = 0; ks < 6; ++ks) {
        s16x8 bb = *(const s16x8*)&W[(size_t)col * 192 + ks * 32 + lq * 8];
        acc0 = MFMA16(a[0][ks], bb, acc0);
        acc1 = MFMA16(a[1][ks], bb, acc1);
      }
      s16x4 pv0, pv1;
#pragma unroll
      for (int q = 0; q < 4; ++q) { pv0[q] = (short)f2bf(acc0[q]); pv1[q] = (short)f2bf(acc1[q]); }
      *(s16x4*)&S.VTs[col][(mh * 2 + 0) * 16 + lq * 4] = pv0;
      *(s16x4*)&S.VTs[col][(mh * 2 + 1) * 16 + lq * 4] = pv1;
    }
  }
  __syncthreads();

  {
    const int mt = wave & 3, g = wave >> 2;
    const int row0 = mt * 16;
#pragma unroll 1
    for (int hh = 0; hh < 3; ++hh) {
      int h = g * 3 + hh;
      s16x8 qa = *(const s16x8*)&S.Qs[row0 + l16][h * 32 + lq * 8];
      f32x4 sv[4];
#pragma unroll
      for (int nt = 0; nt < 4; ++nt) {
        s16x8 kb = *(const s16x8*)&S.Ks[nt * 16 + l16][h * 32 + lq * 8];
        f32x4 z = {0.f, 0.f, 0.f, 0.f};
        sv[nt] = MFMA16(qa, kb, z);
      }
      const unsigned short* rpbh = rpb + h * 4096;
      float lg[4][4];
#pragma unroll
      for (int nt = 0; nt < 4; ++nt) {
        int j = nt * 16 + l16;
#pragma unroll
        for (int q = 0; q < 4; ++q) {
          int i = row0 + lq * 4 + q;
          lg[nt][q] = sv[nt][q] + bf2f(rpbh[i * 64 + j]) + bf2f(S.Ms[i][j]);
        }
      }
#pragma unroll
      for (int q = 0; q < 4; ++q) {
        float m = fmaxf(fmaxf(lg[0][q], lg[1][q]), fmaxf(lg[2][q], lg[3][q]));
#pragma unroll
        for (int s = 1; s < 16; s <<= 1) m = fmaxf(m, __shfl_xor(m, s, 64));
        float p[4], sum = 0.f;
#pragma unroll
        for (int nt = 0; nt < 4; ++nt) { p[nt] = __expf(lg[nt][q] - m); sum += p[nt]; }
#pragma unroll
        for (int s = 1; s < 16; s <<= 1) sum += __shfl_xor(sum, s, 64);
        float r = 1.0f / sum;
#pragma unroll
        for (int nt = 0; nt < 4; ++nt)
          S.Ps[g][row0 + lq * 4 + q][nt * 16 + l16] = f2bf(p[nt] * r);
      }
      f32x4 oacc[2] = {{0.f, 0.f, 0.f, 0.f}, {0.f, 0.f, 0.f, 0.f}};
#pragma unroll
      for (int kt = 0; kt < 2; ++kt) {
        s16x8 pa = *(const s16x8*)&S.Ps[g][row0 + l16][kt * 32 + lq * 8];
#pragma unroll
        for (int n2 = 0; n2 < 2; ++n2) {
          s16x8 vb = *(const s16x8*)&S.VTs[h * 32 + n2 * 16 + l16][kt * 32 + lq * 8];
          oacc[n2] = MFMA16(pa, vb, oacc[n2]);
        }
      }
#pragma unroll
      for (int n2 = 0; n2 < 2; ++n2)
#pragma unroll
        for (int q = 0; q < 4; ++q)
          S.Xs[1][row0 + lq * 4 + q][h * 32 + n2 * 16 + l16] = f2bf(oacc[n2][q]);
    }
  }
  __syncthreads();

  {
    const unsigned short* W = wt + 3 * 36864;
    float* ob = out + (size_t)b * 12288;
    s16x8 a[2][6];
#pragma unroll
    for (int mi = 0; mi < 2; ++mi)
#pragma unroll
      for (int ks = 0; ks < 6; ++ks)
        a[mi][ks] = *(const s16x8*)&S.Xs[1][(mh * 2 + mi) * 16 + l16][ks * 32 + lq * 8];
#pragma unroll
    for (int nt2 = 0; nt2 < 3; ++nt2) {
      int col = (nh * 3 + nt2) * 16 + l16;
      float bsv = bp[col];
      f32x4 acc0 = {bsv, bsv, bsv, bsv};
      f32x4 acc1 = {bsv, bsv, bsv, bsv};
#pragma unroll
      for (int ks = 0; ks < 6; ++ks) {
        s16x8 bb = *(const s16x8*)&W[(size_t)col * 192 + ks * 32 + lq * 8];
        acc0 = MFMA16(a[0][ks], bb, acc0);
        acc1 = MFMA16(a[1][ks], bb, acc1);
      }
#pragma unroll
      for (int q = 0; q < 4; ++q) {
        ob[((mh * 2 + 0) * 16 + lq * 4 + q) * 192 + col] = acc0[q];
        ob[((mh * 2 + 1) * 16 + lq * 4 + q) * 192 + col] = acc1[q];
      }
    }
  }
}

extern "C" void kernel_launch(void* const* d_in, const int* in_sizes, int n_in,
                              void* d_out, int out_size, void* d_ws, size_t ws_size,
                              hipStream_t stream) {
  const float* X1 = (const float*)d_in[0];
  const float* X2 = (const float*)d_in[1];
  const float* X3 = (const float*)d_in[2];
  const float* mask = (const float*)d_in[3];
  const float* Wq = (const float*)d_in[4];
  const float* bq = (const float*)d_in[5];
  const float* Wk = (const float*)d_in[6];
  const float* bk = (const float*)d_in[7];
  const float* Wv = (const float*)d_in[8];
  const float* bv = (const float*)d_in[9];
  const float* Wp = (const float*)d_in[10];
  const float* bp = (const float*)d_in[11];
  const float* bt = (const float*)d_in[12];

  unsigned short* wt = (unsigned short*)d_ws;
  unsigned short* rpb = wt + 4 * 36864;

  int B_ = in_sizes[0] / 12288;
  int nW = in_sizes[3] / 4096;

  prep_weights<<<576, 256, 0, stream>>>(Wq, Wk, Wv, Wp, wt);
  prep_rpb<<<96, 256, 0, stream>>>(bt, rpb);

  const size_t qkv_off = 344064;                        // wt (294912) + rpb (49152)
  const size_t need = qkv_off + (size_t)B_ * 73728;

  if (ws_size >= need) {
    char* qkv = (char*)d_ws + qkv_off;
    (void)hipFuncSetAttribute((const void*)pass1_proj,
                              hipFuncAttributeMaxDynamicSharedMemorySize, 50176);
    pass1_proj<<<3 * B_, 256, 50176, stream>>>(X1, X2, X3, bq, bk, bv, wt, qkv, B_);
    (void)hipFuncSetAttribute((const void*)pass2_attn,
                              hipFuncAttributeMaxDynamicSharedMemorySize, 75776);
    pass2_attn<<<B_, 512, 75776, stream>>>(qkv, mask, rpb, bp, wt,
                                           (float*)d_out, nW);
  } else {
    (void)hipFuncSetAttribute((const void*)win_attn_fused,
                              hipFuncAttributeMaxDynamicSharedMemorySize,
                              (int)sizeof(SmemF));
    win_attn_fused<<<B_, 512, sizeof(SmemF), stream>>>(
        X1, X2, X3, mask, bq, bk, bv, bp, wt, rpb, (float*)d_out, nW);
  }
}

// Round 20
// 374.215 us; speedup vs baseline: 1.0843x; 1.0843x over previous
//
#include <hip/hip_runtime.h>
#include <hip/hip_bf16.h>
#include <stdint.h>

typedef short s16x8 __attribute__((ext_vector_type(8)));
typedef short s16x4 __attribute__((ext_vector_type(4)));
typedef float f32x4 __attribute__((ext_vector_type(4)));

#define MFMA16(a, b, c) __builtin_amdgcn_mfma_f32_16x16x32_bf16((a), (b), (c), 0, 0, 0)

__device__ __forceinline__ unsigned short f2bf(float f) {
  union { float f; uint32_t u; } x; x.f = f;
  uint32_t u = x.u;
  return (unsigned short)((u + 0x7FFFu + ((u >> 16) & 1u)) >> 16);
}
__device__ __forceinline__ float bf2f(unsigned short h) {
  union { uint32_t u; float f; } x; x.u = ((uint32_t)h) << 16;
  return x.f;
}
__device__ __forceinline__ void glds16(const void* g, void* l) {
  __builtin_amdgcn_global_load_lds((const __attribute__((address_space(1))) void*)g,
                                   (__attribute__((address_space(3))) void*)l, 16, 0, 0);
}

// ---------------- prep kernels ----------------
// ws: wt[4][192][192] bf16 (Wt[n][k]=W[k][n]) | rpb[6][64][64] bf16 | QKV scratch
__global__ __launch_bounds__(256) void prep_weights(
    const float* __restrict__ Wq, const float* __restrict__ Wk,
    const float* __restrict__ Wv, const float* __restrict__ Wp,
    unsigned short* __restrict__ wt) {
  int idx = blockIdx.x * 256 + threadIdx.x;
  if (idx >= 4 * 36864) return;
  int mat = idx / 36864, rem = idx % 36864;
  int n = rem / 192, k = rem % 192;
  const float* W = (mat == 0) ? Wq : (mat == 1) ? Wk : (mat == 2) ? Wv : Wp;
  wt[idx] = f2bf(W[k * 192 + n]);
}

__global__ __launch_bounds__(256) void prep_rpb(
    const float* __restrict__ bias_table, unsigned short* __restrict__ rpb) {
  int idx = blockIdx.x * 256 + threadIdx.x;
  if (idx >= 6 * 4096) return;
  int h = idx / 4096, r = idx % 4096;
  int i = r >> 6, j = r & 63;
  int dh = (i >> 3) - (j >> 3) + 7;
  int dw = (i & 7) - (j & 7) + 7;
  rpb[idx] = f2bf(bias_table[(dh * 15 + dw) * 6 + h]);
}

// ---------------- pass 1 (r12: reg-staged bf16 X, 3 blocks/CU, VGPR 76) ------
// Per-window scratch (73728 B):
//   [Q 64x192 bf16 chunk-swizzled | K same | VT 192x64 bf16 k-permuted+swizzled]
__global__ __launch_bounds__(256, 3) void pass1_proj(
    const float* __restrict__ X1g, const float* __restrict__ X2g,
    const float* __restrict__ X3g,
    const float* __restrict__ bq, const float* __restrict__ bk,
    const float* __restrict__ bv,
    const unsigned short* __restrict__ wt,
    char* __restrict__ qkv, int B_) {
  extern __shared__ char p1lds[];   // [0,25600): X bf16 [64][200]; [25600,50176): out
  unsigned short* xs = (unsigned short*)p1lds;
  char* ob = p1lds + 25600;
  const int which = blockIdx.x / B_;
  const int w = blockIdx.x - which * B_;
  const int tid = threadIdx.x;
  const int lane = tid & 63;
  const int wv = tid >> 6;
  const int l16 = lane & 15, lq = lane >> 4;
  const float* Xb =
      ((which == 0) ? X1g : (which == 1) ? X2g : X3g) + (size_t)w * 12288;
  const unsigned short* W = wt + which * 36864;
  const int nt0 = wv * 3;

  // reg-stage X: 6 float8-pairs per thread (coalesced)
  const float4* Xb4 = (const float4*)Xb;
  float4 xr[12];
#pragma unroll
  for (int r = 0; r < 6; ++r) {
    int p = r * 256 + tid;           // pair index 0..1535
    xr[2 * r]     = Xb4[2 * p];
    xr[2 * r + 1] = Xb4[2 * p + 1];
  }

  // weight fragments + bias (L2; latency hides under X loads)
  s16x8 wf[3][6];
#pragma unroll
  for (int t = 0; t < 3; ++t) {
    const unsigned short* wc = W + (size_t)((nt0 + t) * 16 + l16) * 192 + lq * 8;
#pragma unroll
    for (int ks = 0; ks < 6; ++ks) wf[t][ks] = *(const s16x8*)(wc + ks * 32);
  }
  f32x4 bqk[3];
  float bvv[3];
  if (which < 2) {
    const float* bias = which ? bk : bq;
#pragma unroll
    for (int t = 0; t < 3; ++t)
      bqk[t] = *(const f32x4*)&bias[(nt0 + t) * 16 + lq * 4];
  } else {
#pragma unroll
    for (int t = 0; t < 3; ++t) bvv[t] = bv[(nt0 + t) * 16 + l16];
  }

  // convert + write bf16 X tile [64][200]
#pragma unroll
  for (int r = 0; r < 6; ++r) {
    int p = r * 256 + tid;
    int row = p / 24, k8 = p - row * 24;
    const float4& a = xr[2 * r];
    const float4& c = xr[2 * r + 1];
    s16x8 t;
    t[0] = (short)f2bf(a.x); t[1] = (short)f2bf(a.y);
    t[2] = (short)f2bf(a.z); t[3] = (short)f2bf(a.w);
    t[4] = (short)f2bf(c.x); t[5] = (short)f2bf(c.y);
    t[6] = (short)f2bf(c.z); t[7] = (short)f2bf(c.w);
    *(s16x8*)&xs[row * 200 + k8 * 8] = t;
  }
  __syncthreads();

  const float scale = (which == 0) ? 0.17677669529663689f : 1.0f;  // 32^-0.5

#pragma unroll
  for (int mi = 0; mi < 4; ++mi) {
    s16x8 xf[6];
    const unsigned short* pr = xs + (mi * 16 + l16) * 200 + lq * 8;
#pragma unroll
    for (int ks = 0; ks < 6; ++ks) xf[ks] = *(const s16x8*)(pr + ks * 32);
    if (which < 2) {
      // swapped mfma: D[dim rows, tok cols]; lane: tok = mi*16+l16, dims lq*4..+3
      int tok = mi * 16 + l16;
#pragma unroll
      for (int t = 0; t < 3; ++t) {
        f32x4 acc = bqk[t];
#pragma unroll
        for (int ks = 0; ks < 6; ++ks) acc = MFMA16(wf[t][ks], xf[ks], acc);
        s16x4 pv;
#pragma unroll
        for (int q = 0; q < 4; ++q) pv[q] = (short)f2bf(acc[q] * scale);
        int c = (nt0 + t) * 2 + (lq >> 1);                    // 16B chunk (dims c*8..)
        *(s16x4*)(ob + tok * 384 + ((c ^ (tok & 7)) << 4) + (lq & 1) * 8) = pv;
      }
    } else {
      // unswapped: D[tok rows, dim cols]; VT[d][slot], slot k-permuted+swizzled
#pragma unroll
      for (int t = 0; t < 3; ++t) {
        f32x4 acc = {bvv[t], bvv[t], bvv[t], bvv[t]};
#pragma unroll
        for (int ks = 0; ks < 6; ++ks) acc = MFMA16(xf[ks], wf[t][ks], acc);
        int d = (nt0 + t) * 16 + l16;
        int c = (mi >> 1) * 4 + lq;
        s16x4 pv;
#pragma unroll
        for (int q = 0; q < 4; ++q) pv[q] = (short)f2bf(acc[q]);
        *(s16x4*)(ob + d * 128 + ((c ^ (d & 7)) << 4) + (mi & 1) * 8) = pv;
      }
    }
  }
  __syncthreads();

  // copy out-image -> global, full-line coalesced (1536 chunks of 16B)
  char* gdst = qkv + (size_t)w * 73728 + which * 24576;
#pragma unroll
  for (int r = 0; r < 6; ++r) {
    int i = (r * 256 + tid) * 16;
    *(float4*)(gdst + i) = *(const float4*)(ob + i);
  }
}

// ---------------- pass 2 (r10/r12 version: 2 blocks/CU, per-head interleave) --
// LDS: [K 24576 swz | VT 24576 swz | O 64x208 u16 = 26624] = 75776 B
__global__ __launch_bounds__(512, 4) void pass2_attn(
    const char* __restrict__ qkv, const float* __restrict__ maskg,
    const unsigned short* __restrict__ rpb, const float* __restrict__ bp,
    const unsigned short* __restrict__ wt, float* __restrict__ out, int nW) {
  extern __shared__ char lds[];
  const int b = blockIdx.x, tid = threadIdx.x;
  const int wv = tid >> 6, lane = tid & 63;
  const int l16 = lane & 15, lq = lane >> 4;
  const char* Qg = qkv + (size_t)b * 73728;       // swizzled layout (see pass1)
  const char* KVsrc = Qg + 24576;

  // stage K + VT (pre-swizzled by pass1, linear copy): 3072 chunks, 6 rounds
#pragma unroll
  for (int r = 0; r < 6; ++r)
    glds16(KVsrc + (size_t)(r * 512 + tid) * 16, lds + (r * 512 + wv * 64) * 16);

  // register prefetch (completes under the staging drain)
  const int mt = wv & 3, g = wv >> 2;
  const int row0 = mt * 16, qg = row0 + l16;
  s16x8 qf[3];
#pragma unroll
  for (int hh = 0; hh < 3; ++hh) {
    int c = (g * 3 + hh) * 4 + lq;                 // chunk = dim/8
    qf[hh] = *(const s16x8*)(Qg + qg * 384 + ((c ^ (qg & 7)) << 4));
  }
  const float* mrow = maskg + (size_t)(b % nW) * 4096 + qg * 64;
  f32x4 mv[4];
#pragma unroll
  for (int nt = 0; nt < 4; ++nt) mv[nt] = *(const f32x4*)(mrow + nt * 16 + lq * 4);
  s16x4 rv[3][4];
#pragma unroll
  for (int hh = 0; hh < 3; ++hh)
#pragma unroll
    for (int nt = 0; nt < 4; ++nt)
      rv[hh][nt] = *(const s16x4*)&rpb[(g * 3 + hh) * 4096 + qg * 64 + nt * 16 + lq * 4];
  __syncthreads();

  unsigned short* Osm = (unsigned short*)(lds + 49152);   // [64][208]
#pragma unroll
  for (int hh = 0; hh < 3; ++hh) {
    int h = g * 3 + hh;
    f32x4 sv[4];
#pragma unroll
    for (int nt = 0; nt < 4; ++nt) {
      int kr = nt * 16 + l16;
      s16x8 ka = *(const s16x8*)(lds + kr * 384 + (((h * 4 + lq) ^ (kr & 7)) << 4));
      f32x4 z = {0.f, 0.f, 0.f, 0.f};
      sv[nt] = MFMA16(ka, qf[hh], z);   // lane l16 = q-tok, regs = k-toks
    }
    float lg[4][4];
#pragma unroll
    for (int nt = 0; nt < 4; ++nt)
#pragma unroll
      for (int qr = 0; qr < 4; ++qr)
        lg[nt][qr] = sv[nt][qr] + bf2f((unsigned short)rv[hh][nt][qr]) + mv[nt][qr];
    float mx = lg[0][0];
#pragma unroll
    for (int nt = 0; nt < 4; ++nt)
#pragma unroll
      for (int qr = 0; qr < 4; ++qr) mx = fmaxf(mx, lg[nt][qr]);
    mx = fmaxf(mx, __shfl_xor(mx, 16, 64));
    mx = fmaxf(mx, __shfl_xor(mx, 32, 64));
    float p[4][4], sum = 0.f;
#pragma unroll
    for (int nt = 0; nt < 4; ++nt)
#pragma unroll
      for (int qr = 0; qr < 4; ++qr) {
        p[nt][qr] = __expf(lg[nt][qr] - mx);
        sum += p[nt][qr];
      }
    sum += __shfl_xor(sum, 16, 64);
    sum += __shfl_xor(sum, 32, 64);
    float ri = 1.0f / sum;
    s16x8 pa0, pa1;
#pragma unroll
    for (int r = 0; r < 4; ++r) {
      pa0[r]     = (short)f2bf(p[0][r] * ri);
      pa0[4 + r] = (short)f2bf(p[1][r] * ri);
      pa1[r]     = (short)f2bf(p[2][r] * ri);
      pa1[4 + r] = (short)f2bf(p[3][r] * ri);
    }
    // PV: P (regs) x VT (LDS, k-permuted + swizzled)
    f32x4 o0 = {0.f, 0.f, 0.f, 0.f};
    f32x4 o1 = {0.f, 0.f, 0.f, 0.f};
#pragma unroll
    for (int kt = 0; kt < 2; ++kt) {
      int d0 = h * 32 + l16, d1 = h * 32 + 16 + l16;
      s16x8 vb0 = *(const s16x8*)(lds + 24576 + d0 * 128 +
                                  ((((kt << 2) + lq) ^ (d0 & 7)) << 4));
      s16x8 vb1 = *(const s16x8*)(lds + 24576 + d1 * 128 +
                                  ((((kt << 2) + lq) ^ (d1 & 7)) << 4));
      o0 = MFMA16(kt ? pa1 : pa0, vb0, o0);
      o1 = MFMA16(kt ? pa1 : pa0, vb1, o1);
    }
#pragma unroll
    for (int q = 0; q < 4; ++q) {
      int row = row0 + lq * 4 + q;
      Osm[row * 208 + h * 32 + l16]      = f2bf(o0[q]);
      Osm[row * 208 + h * 32 + 16 + l16] = f2bf(o1[q]);
    }
  }
  __syncthreads();

  // out = O @ Wp + bp
  {
    const unsigned short* W = wt + 3 * 36864;
    float* obp = out + (size_t)b * 12288;
    const int mh = wv >> 2, nh = wv & 3;
    s16x8 a[2][6];
#pragma unroll
    for (int mi = 0; mi < 2; ++mi)
#pragma unroll
      for (int ks = 0; ks < 6; ++ks)
        a[mi][ks] = *(const s16x8*)&Osm[((mh * 2 + mi) * 16 + l16) * 208 +
                                        ks * 32 + lq * 8];
#pragma unroll
    for (int nt2 = 0; nt2 < 3; ++nt2) {
      int col = (nh * 3 + nt2) * 16 + l16;
      float bsv = bp[col];
      f32x4 acc0 = {bsv, bsv, bsv, bsv};
      f32x4 acc1 = {bsv, bsv, bsv, bsv};
      const unsigned short* wc = W + (size_t)col * 192 + lq * 8;
#pragma unroll
      for (int ks = 0; ks < 6; ++ks) {
        s16x8 bb = *(const s16x8*)(wc + ks * 32);
        acc0 = MFMA16(a[0][ks], bb, acc0);
        acc1 = MFMA16(a[1][ks], bb, acc1);
      }
#pragma unroll
      for (int q = 0; q < 4; ++q) {
        obp[((mh * 2 + 0) * 16 + lq * 4 + q) * 192 + col] = acc0[q];
        obp[((mh * 2 + 1) * 16 + lq * 4 + q) * 192 + col] = acc1[q];
      }
    }
  }
}

// ---------------- fallback: r1 fused single kernel (proven) ----------------
#define XPAD 200
#define VPAD 72
#define PPAD 72
#define MPAD 66
struct SmemF {
  unsigned short Xs[2][64][XPAD];
  unsigned short Qs[64][XPAD];
  unsigned short Ks[64][XPAD];
  unsigned short VTs[192][VPAD];
  unsigned short Ps[2][64][PPAD];
  unsigned short Ms[64][MPAD];
};

__global__ __launch_bounds__(512, 2) void win_attn_fused(
    const float* __restrict__ X1g, const float* __restrict__ X2g,
    const float* __restrict__ X3g, const float* __restrict__ maskg,
    const float* __restrict__ bq, const float* __restrict__ bk,
    const float* __restrict__ bv, const float* __restrict__ bp,
    const unsigned short* __restrict__ wt, const unsigned short* __restrict__ rpb,
    float* __restrict__ out, int nW) {
  extern __shared__ char smem_raw[];
  SmemF& S = *reinterpret_cast<SmemF*>(smem_raw);
  const int b = blockIdx.x;
  const int tid = threadIdx.x;
  const int wave = tid >> 6, lane = tid & 63;
  const int l16 = lane & 15, lq = lane >> 4;
  const int mh = wave >> 2, nh = wave & 3;

  const float4* x1v = (const float4*)(X1g + (size_t)b * 12288);
  const float4* x2v = (const float4*)(X2g + (size_t)b * 12288);
  const float4* x3v = (const float4*)(X3g + (size_t)b * 12288);
  float4 x3r[6];
#pragma unroll
  for (int it = 0; it < 6; ++it) {
    int i = it * 512 + tid;
    float4 v1 = x1v[i];
    float4 v2 = x2v[i];
    x3r[it] = x3v[i];
    int row = i / 48, c = (i % 48) * 4;
    s16x4 p1, p2;
    p1[0] = (short)f2bf(v1.x); p1[1] = (short)f2bf(v1.y);
    p1[2] = (short)f2bf(v1.z); p1[3] = (short)f2bf(v1.w);
    p2[0] = (short)f2bf(v2.x); p2[1] = (short)f2bf(v2.y);
    p2[2] = (short)f2bf(v2.z); p2[3] = (short)f2bf(v2.w);
    *(s16x4*)&S.Xs[0][row][c] = p1;
    *(s16x4*)&S.Xs[1][row][c] = p2;
  }
  const float* mw = maskg + (size_t)(b % nW) * 4096;
  for (int i = tid; i < 4096; i += 512)
    S.Ms[i >> 6][i & 63] = f2bf(mw[i]);
  __syncthreads();

  auto proj = [&](const unsigned short (*Xsrc)[XPAD], const unsigned short* W,
                  const float* bias, unsigned short (*dst)[XPAD], float scale) {
    s16x8 a[2][6];
#pragma unroll
    for (int mi = 0; mi < 2; ++mi)
#pragma unroll
      for (int ks = 0; ks < 6; ++ks)
        a[mi][ks] = *(const s16x8*)&Xsrc[(mh * 2 + mi) * 16 + l16][ks * 32 + lq * 8];
#pragma unroll
    for (int nt2 = 0; nt2 < 3; ++nt2) {
      int col = (nh * 3 + nt2) * 16 + l16;
      float bsv = bias[col];
      f32x4 acc0 = {bsv, bsv, bsv, bsv};
      f32x4 acc1 = {bsv, bsv, bsv, bsv};
#pragma unroll
      for (int ks = 0; ks < 6; ++ks) {
        s16x8 bb = *(const s16x8*)&W[(size_t)col * 192 + ks * 32 + lq * 8];
        acc0 = MFMA16(a[0][ks], bb, acc0);
        acc1 = MFMA16(a[1][ks], bb, acc1);
      }
#pragma unroll
      for (int q = 0; q < 4; ++q) {
        dst[(mh * 2 + 0) * 16 + lq * 4 + q][col] = f2bf(acc0[q] * scale);
        dst[(mh * 2 + 1) * 16 + lq * 4 + q][col] = f2bf(acc1[q] * scale);
      }
    }
  };

  proj(S.Xs[0], wt + 0 * 36864, bq, S.Qs, 0.17677669529663689f);
  proj(S.Xs[1], wt + 1 * 36864, bk, S.Ks, 1.0f);
  __syncthreads();

#pragma unroll
  for (int it = 0; it < 6; ++it) {
    int i = it * 512 + tid;
    int row = i / 48, c = (i % 48) * 4;
    s16x4 p3;
    p3[0] = (short)f2bf(x3r[it].x); p3[1] = (short)f2bf(x3r[it].y);
    p3[2] = (short)f2bf(x3r[it].z); p3[3] = (short)f2bf(x3r[it].w);
    *(s16x4*)&S.Xs[0][row][c] = p3;
  }
  __syncthreads();

  {
    const unsigned short* W = wt + 2 * 36864;
    s16x8 a[2][6];
#pragma unroll
    for (int mi = 0; mi < 2; ++mi)
#pragma unroll
      for (int ks = 0; ks < 6; ++ks)
        a[mi][ks] = *(const s16x8*)&S.Xs[0][(mh * 2 + mi) * 16 + l16][ks * 32 + lq * 8];
#pragma unroll
    for (int nt2 = 0; nt2 < 3; ++nt2) {
      int col = (nh * 3 + nt2) * 16 + l16;
      float bsv = bv[col];
      f32x4 acc0 = {bsv, bsv, bsv, bsv};
      f32x4 acc1 = {bsv, bsv, bsv, bsv};
#pragma unroll
      for (int ks = 0; ks < 6; ++ks) {
        s16x8 bb = *(const s16x8*)&W[(size_t)col * 192 + ks * 32 + lq * 8];
        acc0 = MFMA16(a[0][ks], bb, acc0);
        acc1 = MFMA16(a[1][ks], bb, acc1);
      }
      s16x4 pv0, pv1;
#pragma unroll
      for (int q = 0; q < 4; ++q) { pv0[q] = (short)f2bf(acc0[q]); pv1[q] = (short)f2bf(acc1[q]); }
      *(s16x4*)&S.VTs[col][(mh * 2 + 0) * 16 + lq * 4] = pv0;
      *(s16x4*)&S.VTs[col][(mh * 2 + 1) * 16 + lq * 4] = pv1;
    }
  }
  __syncthreads();

  {
    const int mt = wave & 3, g = wave >> 2;
    const int row0 = mt * 16;
#pragma unroll 1
    for (int hh = 0; hh < 3; ++hh) {
      int h = g * 3 + hh;
      s16x8 qa = *(const s16x8*)&S.Qs[row0 + l16][h * 32 + lq * 8];
      f32x4 sv[4];
#pragma unroll
      for (int nt = 0; nt < 4; ++nt) {
        s16x8 kb = *(const s16x8*)&S.Ks[nt * 16 + l16][h * 32 + lq * 8];
        f32x4 z = {0.f, 0.f, 0.f, 0.f};
        sv[nt] = MFMA16(qa, kb, z);
      }
      const unsigned short* rpbh = rpb + h * 4096;
      float lg[4][4];
#pragma unroll
      for (int nt = 0; nt < 4; ++nt) {
        int j = nt * 16 + l16;
#pragma unroll
        for (int q = 0; q < 4; ++q) {
          int i = row0 + lq * 4 + q;
          lg[nt][q] = sv[nt][q] + bf2f(rpbh[i * 64 + j]) + bf2f(S.Ms[i][j]);
        }
      }
#pragma unroll
      for (int q = 0; q < 4; ++q) {
        float m = fmaxf(fmaxf(lg[0][q], lg[1][q]), fmaxf(lg[2][q], lg[3][q]));
#pragma unroll
        for (int s = 1; s < 16; s <<= 1) m = fmaxf(m, __shfl_xor(m, s, 64));
        float p[4], sum = 0.f;
#pragma unroll
        for (int nt = 0; nt < 4; ++nt) { p[nt] = __expf(lg[nt][q] - m); sum += p[nt]; }
#pragma unroll
        for (int s = 1; s < 16; s <<= 1) sum += __shfl_xor(sum, s, 64);
        float r = 1.0f / sum;
#pragma unroll
        for (int nt = 0; nt < 4; ++nt)
          S.Ps[g][row0 + lq * 4 + q][nt * 16 + l16] = f2bf(p[nt] * r);
      }
      f32x4 oacc[2] = {{0.f, 0.f, 0.f, 0.f}, {0.f, 0.f, 0.f, 0.f}};
#pragma unroll
      for (int kt = 0; kt < 2; ++kt) {
        s16x8 pa = *(const s16x8*)&S.Ps[g][row0 + l16][kt * 32 + lq * 8];
#pragma unroll
        for (int n2 = 0; n2 < 2; ++n2) {
          s16x8 vb = *(const s16x8*)&S.VTs[h * 32 + n2 * 16 + l16][kt * 32 + lq * 8];
          oacc[n2] = MFMA16(pa, vb, oacc[n2]);
        }
      }
#pragma unroll
      for (int n2 = 0; n2 < 2; ++n2)
#pragma unroll
        for (int q = 0; q < 4; ++q)
          S.Xs[1][row0 + lq * 4 + q][h * 32 + n2 * 16 + l16] = f2bf(oacc[n2][q]);
    }
  }
  __syncthreads();

  {
    const unsigned short* W = wt + 3 * 36864;
    float* ob = out + (size_t)b * 12288;
    s16x8 a[2][6];
#pragma unroll
    for (int mi = 0; mi < 2; ++mi)
#pragma unroll
      for (int ks = 0; ks < 6; ++ks)
        a[mi][ks] = *(const s16x8*)&S.Xs[1][(mh * 2 + mi) * 16 + l16][ks * 32 + lq * 8];
#pragma unroll
    for (int nt2 = 0; nt2 < 3; ++nt2) {
      int col = (nh * 3 + nt2) * 16 + l16;
      float bsv = bp[col];
      f32x4 acc0 = {bsv, bsv, bsv, bsv};
      f32x4 acc1 = {bsv, bsv, bsv, bsv};
#pragma unroll
      for (int ks = 0; ks < 6; ++ks) {
        s16x8 bb = *(const s16x8*)&W[(size_t)col * 192 + ks * 32 + lq * 8];
        acc0 = MFMA16(a[0][ks], bb, acc0);
        acc1 = MFMA16(a[1][ks], bb, acc1);
      }
#pragma unroll
      for (int q = 0; q < 4; ++q) {
        ob[((mh * 2 + 0) * 16 + lq * 4 + q) * 192 + col] = acc0[q];
        ob[((mh * 2 + 1) * 16 + lq * 4 + q) * 192 + col] = acc1[q];
      }
    }
  }
}

extern "C" void kernel_launch(void* const* d_in, const int* in_sizes, int n_in,
                              void* d_out, int out_size, void* d_ws, size_t ws_size,
                              hipStream_t stream) {
  const float* X1 = (const float*)d_in[0];
  const float* X2 = (const float*)d_in[1];
  const float* X3 = (const float*)d_in[2];
  const float* mask = (const float*)d_in[3];
  const float* Wq = (const float*)d_in[4];
  const float* bq = (const float*)d_in[5];
  const float* Wk = (const float*)d_in[6];
  const float* bk = (const float*)d_in[7];
  const float* Wv = (const float*)d_in[8];
  const float* bv = (const float*)d_in[9];
  const float* Wp = (const float*)d_in[10];
  const float* bp = (const float*)d_in[11];
  const float* bt = (const float*)d_in[12];

  unsigned short* wt = (unsigned short*)d_ws;
  unsigned short* rpb = wt + 4 * 36864;

  int B_ = in_sizes[0] / 12288;
  int nW = in_sizes[3] / 4096;

  prep_weights<<<576, 256, 0, stream>>>(Wq, Wk, Wv, Wp, wt);
  prep_rpb<<<96, 256, 0, stream>>>(bt, rpb);

  const size_t qkv_off = 344064;                        // wt (294912) + rpb (49152)
  const size_t need = qkv_off + (size_t)B_ * 73728;

  if (ws_size >= need) {
    char* qkv = (char*)d_ws + qkv_off;
    (void)hipFuncSetAttribute((const void*)pass1_proj,
                              hipFuncAttributeMaxDynamicSharedMemorySize, 50176);
    pass1_proj<<<3 * B_, 256, 50176, stream>>>(X1, X2, X3, bq, bk, bv, wt, qkv, B_);
    (void)hipFuncSetAttribute((const void*)pass2_attn,
                              hipFuncAttributeMaxDynamicSharedMemorySize, 75776);
    pass2_attn<<<B_, 512, 75776, stream>>>(qkv, mask, rpb, bp, wt,
                                           (float*)d_out, nW);
  } else {
    (void)hipFuncSetAttribute((const void*)win_attn_fused,
                              hipFuncAttributeMaxDynamicSharedMemorySize,
                              (int)sizeof(SmemF));
    win_attn_fused<<<B_, 512, sizeof(SmemF), stream>>>(
        X1, X2, X3, mask, bq, bk, bv, bp, wt, rpb, (float*)d_out, nW);
  }
}